// Round 3
// baseline (547.160 us; speedup 1.0000x reference)
//
#include <hip/hip_runtime.h>
#include <hip/hip_bf16.h>

// ---------------------------------------------------------------------------
// Fused GQA attention block for B=2,T=2048,D=1024,N=16,K=8,H=128 on gfx950.
// R13: swapped-operand flash. R11/R12 showed 32-rows/wave amortization is
// worthless below 8 waves/CU (latency-bound), and per-chunk S-extent
// variance breaks temporal balance. New structure attacks the LDS floor
// itself: compute QK^T swapped (A=K, B=Q) so P is lane-local (q on l16);
// an s-row permutation on the K-frag load makes P's in-register layout
// exactly the 16x16x32 PV A-operand (s = quad*8+j). Each wave reads only
// its 32-s slice of K/V (16KB/tile vs 34KB); P never touches LDS. O is
// per-wave partial over s (static max => partials add); 3-round LDS
// combine per chunk. 64-row chunks, pairs {31-p,p} = uniform 17 tiles per
// block, grid 512, 64KB LDS -> 2 blocks/CU sustained.
// ---------------------------------------------------------------------------

typedef unsigned short u16;
typedef __attribute__((ext_vector_type(8))) short s16x8;   // 8 bf16 = 4 VGPRs (MFMA A/B frag)
typedef __attribute__((ext_vector_type(4))) float fp32x4;  // MFMA C/D frag
typedef __attribute__((ext_vector_type(4))) u16 u16x4;

#define MFMA_BF16(a, b, c) __builtin_amdgcn_mfma_f32_16x16x32_bf16((a), (b), (c), 0, 0, 0)

static constexpr int Bq = 2, Tq = 2048, Dq = 1024, NHq = 16, KHq = 8, Hq = 128;
static constexpr float EPSq = 1e-6f;
// exp2 domain: logits scaled by SCALE*log2(e); softmax invariant to the base.
static constexpr float S2q = 0.08838834764831845f * 1.4426950408889634f;
static constexpr float MAXq = 20.0f;   // static softmax max (exp2 domain)
static constexpr float NEGHUGE = -3.0e38f;

__device__ __forceinline__ u16 f2b(float f) {
  __hip_bfloat16 h = __float2bfloat16(f);
  return *reinterpret_cast<u16*>(&h);
}

// async global->LDS, 16B per lane; LDS dest = wave-uniform base + lane*16.
__device__ __forceinline__ void gload16(const u16* g, u16* lds_base) {
  __builtin_amdgcn_global_load_lds(
      (const __attribute__((address_space(1))) unsigned int*)(const void*)g,
      (__attribute__((address_space(3))) unsigned int*)(void*)lds_base, 16, 0, 0);
}

// ---------------- merged prep kernel ----------------------------------------
// blocks [0,4096):    cast x -> bf16
// blocks [4096,8192):  wq|wk|wv transpose-cast into fused B^T (4096x1024)
// blocks [8192,10240): wo transpose-cast -> wo_t (1024x2048)
// blocks [10240,10242): positions from segment_ids

__global__ __launch_bounds__(256) void prep_kernel(
    const float* __restrict__ x, const float* __restrict__ wq,
    const float* __restrict__ wk, const float* __restrict__ wv,
    const float* __restrict__ wo, const int* __restrict__ seg,
    u16* __restrict__ xb, u16* __restrict__ wqkv_t, u16* __restrict__ wo_t,
    int* __restrict__ pos) {
  const int bid = blockIdx.x;
  const int tid = threadIdx.x;
  if (bid < 4096) {
    const int i = bid * 1024 + tid * 4;
    const float4 v = *reinterpret_cast<const float4*>(x + i);
    u16x4 o;
    o.x = f2b(v.x); o.y = f2b(v.y); o.z = f2b(v.z); o.w = f2b(v.w);
    *reinterpret_cast<u16x4*>(xb + i) = o;
    return;
  }
  __shared__ float tile[32][33];
  __shared__ int sv[256], si[256];
  const int tx = tid & 31, ty = tid >> 5;
  if (bid < 8192) {
    const int z = bid - 4096;
    const int r0 = (z & 31) * 32;   // D block
    const int c0 = (z >> 5) * 32;   // weight col block (0..4095)
    const float* src;
    int stride, coff;
    if (c0 < 2048)      { src = wq; stride = 2048; coff = c0; }
    else if (c0 < 3072) { src = wk; stride = 1024; coff = c0 - 2048; }
    else                { src = wv; stride = 1024; coff = c0 - 3072; }
#pragma unroll
    for (int j = 0; j < 32; j += 8)
      tile[ty + j][tx] = src[(long)(r0 + ty + j) * stride + (coff + tx)];
    __syncthreads();
#pragma unroll
    for (int j = 0; j < 32; j += 8)
      wqkv_t[(long)(c0 + ty + j) * 1024 + (r0 + tx)] = f2b(tile[tx][ty + j]);
    return;
  }
  if (bid < 10240) {
    const int z = bid - 8192;
    const int c0 = (z & 31) * 32;   // D col block (dst row, 0..1023)
    const int r0 = (z >> 5) * 32;   // src row block (0..2047)
#pragma unroll
    for (int j = 0; j < 32; j += 8)
      tile[ty + j][tx] = wo[(long)(r0 + ty + j) * 1024 + (c0 + tx)];
    __syncthreads();
#pragma unroll
    for (int j = 0; j < 32; j += 8)
      wo_t[(long)(c0 + ty + j) * 2048 + (r0 + tx)] = f2b(tile[tx][ty + j]);
    return;
  }
  // positions
  const int b = bid - 10240;
  const int* s = seg + b * Tq;
  int bestv = -2147483647 - 1, besti = 0x7fffffff;
  for (int t = tid; t < Tq; t += 256) {
    int v = s[t];
    if (v > bestv) { bestv = v; besti = t; }
  }
  sv[tid] = bestv; si[tid] = besti;
  __syncthreads();
  for (int k = 128; k > 0; k >>= 1) {
    if (tid < k) {
      int v2 = sv[tid + k], i2 = si[tid + k];
      if (v2 > sv[tid] || (v2 == sv[tid] && i2 < si[tid])) {
        sv[tid] = v2; si[tid] = i2;
      }
    }
    __syncthreads();
  }
  const int off = si[0];
  for (int t = tid; t < Tq; t += 256)
    pos[b * Tq + t] = (s[t] != 0) ? (t - off) : (1 << 30);
}

// ---------------- QKV GEMM + fused norm/rope/v-transpose --------------------

__global__ __launch_bounds__(256) void gemm_qkv_kernel(
    const u16* __restrict__ A, const u16* __restrict__ Bt,
    u16* __restrict__ qkv, u16* __restrict__ vt, const int* __restrict__ pos,
    const float* __restrict__ q_scale, const float* __restrict__ k_scale) {
  __shared__ __align__(16) u16 As[128][64];
  __shared__ __align__(16) u16 Bs[128][64];
  const int tid = threadIdx.x;
  const int wave = tid >> 6, lane = tid & 63;
  const int quad = lane >> 4, l16 = lane & 15;
  const int m0 = blockIdx.y * 128, n0 = blockIdx.x * 128;
  const int row8 = lane >> 3;
  const int cgl = (lane & 7) ^ row8;

  const fp32x4 z4 = {0.f, 0.f, 0.f, 0.f};
  fp32x4 acc[2][8];
#pragma unroll
  for (int i = 0; i < 2; ++i)
#pragma unroll
    for (int j = 0; j < 8; ++j) acc[i][j] = z4;

  for (int k0 = 0; k0 < 1024; k0 += 64) {
    __syncthreads();
#pragma unroll
    for (int jj = 0; jj < 4; ++jj) {
      const int R = wave * 32 + jj * 8;
      gload16(A + (size_t)(m0 + R + row8) * 1024 + k0 + cgl * 8, &As[R][0]);
      gload16(Bt + (size_t)(n0 + R + row8) * 1024 + k0 + cgl * 8, &Bs[R][0]);
    }
    __syncthreads();
#pragma unroll
    for (int kh = 0; kh < 2; ++kh) {
      s16x8 af[2], bfr[8];
#pragma unroll
      for (int i = 0; i < 2; ++i)
        af[i] = *(const s16x8*)&As[wave * 32 + i * 16 + l16]
                               [((((kh << 2) | quad) ^ (l16 & 7)) << 3)];
#pragma unroll
      for (int j = 0; j < 8; ++j)
        bfr[j] = *(const s16x8*)&Bs[j * 16 + l16]
                                [((((kh << 2) | quad) ^ (l16 & 7)) << 3)];
#pragma unroll
      for (int i = 0; i < 2; ++i)
#pragma unroll
        for (int j = 0; j < 8; ++j) acc[i][j] = MFMA_BF16(af[i], bfr[j], acc[i][j]);
    }
  }

  const int wrow = m0 + wave * 32;
  if (n0 >= 3072) {  // v tile: write transposed directly into vt
    const int kv8 = (n0 - 3072) >> 7;
    const int bq = wrow >> 11;
    const size_t vbase = (size_t)(bq * KHq + kv8) * Hq * Tq;
#pragma unroll
    for (int i = 0; i < 2; ++i) {
      const int t = (wrow + i * 16 + quad * 4) & 2047;
#pragma unroll
      for (int j = 0; j < 8; ++j) {
        const int h = j * 16 + l16;
        u16x4 o;
#pragma unroll
        for (int r = 0; r < 4; ++r) o[r] = f2b(acc[i][j][r]);
        *reinterpret_cast<u16x4*>(&vt[vbase + (size_t)h * Tq + t]) = o;
      }
    }
    return;
  }
  // q or k tile: fused RMS norm + scale + RoPE on fp32 acc
  const float* scp = (n0 < 2048) ? q_scale : k_scale;
  float scl[8];
#pragma unroll
  for (int j = 0; j < 8; ++j) scl[j] = scp[j * 16 + l16];
  float invf[4];
#pragma unroll
  for (int jf = 0; jf < 4; ++jf)  // inv_freq/(2pi): rotations per position
    invf[jf] = __builtin_amdgcn_exp2f(
                   -(float)(jf * 16 + l16) * (19.931568569324174f / 64.0f)) *
               0.15915494309189535f;
#pragma unroll
  for (int i = 0; i < 2; ++i) {
    float ss[4] = {0.f, 0.f, 0.f, 0.f};
#pragma unroll
    for (int j = 0; j < 8; ++j)
#pragma unroll
      for (int r = 0; r < 4; ++r) ss[r] += acc[i][j][r] * acc[i][j][r];
#pragma unroll
    for (int d = 1; d < 16; d <<= 1)
#pragma unroll
      for (int r = 0; r < 4; ++r) ss[r] += __shfl_xor(ss[r], d, 64);
#pragma unroll
    for (int r = 0; r < 4; ++r) {
      const int row = wrow + i * 16 + quad * 4 + r;
      const float rinv = rsqrtf(ss[r] * (1.0f / 128.0f) + EPSq);
      const float P = (float)pos[row];
      u16* orow = qkv + (size_t)row * 4096 + n0;
#pragma unroll
      for (int jf = 0; jf < 4; ++jf) {
        float rev = P * invf[jf];
        rev -= floorf(rev);
        const float s = __builtin_amdgcn_sinf(rev);
        const float c = __builtin_amdgcn_cosf(rev);
        const float a1 = acc[i][jf][r] * rinv * scl[jf];
        const float a2 = acc[i][jf + 4][r] * rinv * scl[jf + 4];
        orow[jf * 16 + l16] = f2b(a1 * c - a2 * s);
        orow[(jf + 4) * 16 + l16] = f2b(a2 * c + a1 * s);
      }
    }
  }
}

// ---------------- out-proj GEMM (fp32 out, BN=64) ---------------------------

__global__ __launch_bounds__(256) void gemm_out_kernel(
    const u16* __restrict__ A, const u16* __restrict__ Bt,
    float* __restrict__ C) {
  __shared__ __align__(16) u16 As[128][64];
  __shared__ __align__(16) u16 Bs[64][64];
  const int tid = threadIdx.x;
  const int wave = tid >> 6, lane = tid & 63;
  const int quad = lane >> 4, l16 = lane & 15;
  const int m0 = blockIdx.y * 128, n0 = blockIdx.x * 64;
  const int wm = (wave >> 1) * 64, wn = (wave & 1) * 32;
  const int row8 = lane >> 3;
  const int cgl = (lane & 7) ^ row8;

  const fp32x4 z4 = {0.f, 0.f, 0.f, 0.f};
  fp32x4 acc[4][2];
#pragma unroll
  for (int i = 0; i < 4; ++i)
#pragma unroll
    for (int j = 0; j < 2; ++j) acc[i][j] = z4;

  for (int k0 = 0; k0 < 2048; k0 += 64) {
    __syncthreads();
#pragma unroll
    for (int jj = 0; jj < 4; ++jj) {
      const int R = wave * 32 + jj * 8;
      gload16(A + (size_t)(m0 + R + row8) * 2048 + k0 + cgl * 8, &As[R][0]);
    }
#pragma unroll
    for (int jj = 0; jj < 2; ++jj) {
      const int R = wave * 16 + jj * 8;
      gload16(Bt + (size_t)(n0 + R + row8) * 2048 + k0 + cgl * 8, &Bs[R][0]);
    }
    __syncthreads();
#pragma unroll
    for (int kh = 0; kh < 2; ++kh) {
      s16x8 af[4], bfr[2];
#pragma unroll
      for (int i = 0; i < 4; ++i)
        af[i] = *(const s16x8*)&As[wm + i * 16 + l16]
                               [((((kh << 2) | quad) ^ (l16 & 7)) << 3)];
#pragma unroll
      for (int j = 0; j < 2; ++j)
        bfr[j] = *(const s16x8*)&Bs[wn + j * 16 + l16]
                                [((((kh << 2) | quad) ^ (l16 & 7)) << 3)];
#pragma unroll
      for (int i = 0; i < 4; ++i)
#pragma unroll
        for (int j = 0; j < 2; ++j) acc[i][j] = MFMA_BF16(af[i], bfr[j], acc[i][j]);
    }
  }
#pragma unroll
  for (int i = 0; i < 4; ++i) {
    const int row = m0 + wm + i * 16 + quad * 4;
#pragma unroll
    for (int j = 0; j < 2; ++j) {
      const int col = n0 + wn + j * 16 + l16;
#pragma unroll
      for (int r = 0; r < 4; ++r)
        C[(size_t)(row + r) * 1024 + col] = acc[i][j][r];
    }
  }
}

// ---------------- flash attention (swapped-operand, wave-S-split) -----------
// Grid 512: block = (b, kv, qh, pair p); chunks {31-p, p} (64 Q rows each),
// uniform 17 x 128-wide S-tiles per block. 4 waves; wave w owns the 32-s
// slice [32w,32w+32) of each tile and ALL 64 Q rows (qf[4][4] as B-frags).
// QK^T computed swapped (A=K-frag with s-row permutation sigma, B=Q) so
// each lane holds P for one q (l16) at s = quad*8+j -- exactly the
// 16x16x32 PV A-operand layout. P stays in registers (no Ps LDS, no
// lgkmcnt stall). O/l are per-wave partials over s; static-max softmax =>
// combine = plain add: 3-round LDS exchange per chunk. K/V single-
// buffered 64KB LDS -> 2 blocks/CU (8 waves/CU) sustained; all frag reads
// XOR-swizzled 16B chunks (<=2-way bank aliasing).

__global__ __launch_bounds__(256, 2) void flash_kernel(
    const u16* __restrict__ qkv, const u16* __restrict__ vt,
    const int* __restrict__ pos, const int* __restrict__ seg,
    u16* __restrict__ Obuf) {
  const int tid = threadIdx.x;
  const int w = tid >> 6;
  const int lane = tid & 63;
  const int quad = lane >> 4, l16 = lane & 15;
  const int g = blockIdx.x;
  const int u = g & 31;            // unit: XCD gets 4 units = 2 K/V sets (L2-fit)
  const int b = u & 1;
  const int kv = (u >> 1) & 7;
  const int qh = kv * 2 + ((u >> 4) & 1);
  const int p = g >> 5;            // 0..15 -> chunks {31-p, p}

  __shared__ __align__(16) u16 Ks[128][128];   // [s][h-chunk ^ (s&15)]
  __shared__ __align__(16) u16 Vs[128][128];   // [h][s-chunk ^ (h&15)]

  const u16* kbase = qkv + (size_t)(b * Tq) * 4096 + 2048 + kv * Hq;
  const u16* vbase = vt + (size_t)(b * KHq + kv) * Hq * Tq;
  const int ro = lane >> 4;        // staging row offset 0..3
  const int ch = lane & 15;        // staging 16B-chunk index
  const fp32x4 z4 = {0.f, 0.f, 0.f, 0.f};

#pragma unroll
  for (int half = 0; half < 2; ++half) {
    const int c = half ? p : 31 - p;      // heavy chunk first
    const int t0 = c * 64;
    const int nst = (c + 2) >> 1;         // ceil((c+1)/2) 128-wide S-tiles

    // Q for ALL 64 chunk rows, as B-frags: lane col=l16 -> q, k=quad*8+j -> h
    s16x8 qf[4][4];
#pragma unroll
    for (int qb = 0; qb < 4; ++qb)
#pragma unroll
      for (int hk = 0; hk < 4; ++hk)
        qf[qb][hk] = *(const s16x8*)(qkv +
            (size_t)(b * Tq + t0 + qb * 16 + l16) * 4096 + qh * Hq +
            hk * 32 + quad * 8);

    fp32x4 o_acc[4][8];                   // [qb][hb] partial over wave's s
#pragma unroll
    for (int qb = 0; qb < 4; ++qb)
#pragma unroll
      for (int hb = 0; hb < 8; ++hb) o_acc[qb][hb] = z4;
    float l_lane[4] = {0.f, 0.f, 0.f, 0.f};

    for (int st = 0; st < nst; ++st) {
      const int s0 = st * 128;
      __syncthreads();  // all waves done with previous tile / combine buffers
#pragma unroll
      for (int jj = 0; jj < 8; ++jj) {
        const int R = w * 32 + jj * 4;
        const int srow = R + ro;
        gload16(kbase + (size_t)(s0 + srow) * 4096 + ((ch ^ (srow & 15)) << 3),
                &Ks[R][0]);
      }
#pragma unroll
      for (int jj = 0; jj < 8; ++jj) {
        const int R = w * 32 + jj * 4;
        const int hrow = R + ro;
        gload16(vbase + (size_t)hrow * Tq + s0 + ((ch ^ (hrow & 15)) << 3),
                &Vs[R][0]);
      }
      __syncthreads();  // drains vmcnt: tile visible

      // QK^T swapped: sc[qb][sh]; D col=l16=q, row -> s = w*32+quad*8+sh*4+r
      fp32x4 sc[4][2];
#pragma unroll
      for (int qb = 0; qb < 4; ++qb) { sc[qb][0] = z4; sc[qb][1] = z4; }
      __builtin_amdgcn_s_setprio(1);
#pragma unroll
      for (int hk = 0; hk < 4; ++hk) {
        s16x8 kf[2];
#pragma unroll
        for (int sh = 0; sh < 2; ++sh) {
          // sigma: frag row l16 -> s-row 8*(l16>>2) + 4*sh + (l16&3)
          const int srow = w * 32 + ((l16 >> 2) << 3) + (sh << 2) + (l16 & 3);
          const int hc = hk * 4 + quad;
          kf[sh] = *(const s16x8*)&Ks[srow][((hc ^ (srow & 15)) << 3)];
        }
#pragma unroll
        for (int qb = 0; qb < 4; ++qb) {
          sc[qb][0] = MFMA_BF16(kf[0], qf[qb][hk], sc[qb][0]);
          sc[qb][1] = MFMA_BF16(kf[1], qf[qb][hk], sc[qb][1]);
        }
      }
      __builtin_amdgcn_s_setprio(0);

      if (st == nst - 1) {  // diagonal tile: causal + segment mask
        int qpos[4], qseg[4];
#pragma unroll
        for (int qb = 0; qb < 4; ++qb) {
          const int q = t0 + qb * 16 + l16;
          qpos[qb] = pos[b * Tq + q];
          qseg[qb] = seg[b * Tq + q];
        }
        int spos[2][4], sseg[2][4];
#pragma unroll
        for (int sh = 0; sh < 2; ++sh)
#pragma unroll
          for (int r = 0; r < 4; ++r) {
            const int s = s0 + w * 32 + quad * 8 + sh * 4 + r;
            spos[sh][r] = pos[b * Tq + s];
            sseg[sh][r] = seg[b * Tq + s];
          }
#pragma unroll
        for (int qb = 0; qb < 4; ++qb)
#pragma unroll
          for (int sh = 0; sh < 2; ++sh)
#pragma unroll
            for (int r = 0; r < 4; ++r) {
              const bool ok = (sseg[sh][r] == qseg[qb]) &&
                              (spos[sh][r] <= qpos[qb]);
              sc[qb][sh][r] = ok ? sc[qb][sh][r] * S2q - MAXq : NEGHUGE;
            }
      } else {
#pragma unroll
        for (int qb = 0; qb < 4; ++qb)
#pragma unroll
          for (int sh = 0; sh < 2; ++sh)
#pragma unroll
            for (int r = 0; r < 4; ++r)
              sc[qb][sh][r] = sc[qb][sh][r] * S2q - MAXq;
      }

      // exp2 + in-register pack: p8[qb] element j=4*sh+r -> s=quad*8+j.
      s16x8 p8[4];
#pragma unroll
      for (int qb = 0; qb < 4; ++qb) {
#pragma unroll
        for (int sh = 0; sh < 2; ++sh)
#pragma unroll
          for (int r = 0; r < 4; ++r) {
            const float e = __builtin_amdgcn_exp2f(sc[qb][sh][r]);
            l_lane[qb] += e;
            p8[qb][sh * 4 + r] = (short)f2b(e);
          }
      }

      // PV: O[q][h] += P * V; vf lane: col=l16=h, k=quad*8+j -> s
      __builtin_amdgcn_s_setprio(1);
#pragma unroll
      for (int hb = 0; hb < 8; ++hb) {
        const int h = hb * 16 + l16;
        const int sch = w * 4 + quad;
        const s16x8 vf = *(const s16x8*)&Vs[h][((sch ^ (h & 15)) << 3)];
#pragma unroll
        for (int qb = 0; qb < 4; ++qb)
          o_acc[qb][hb] = MFMA_BF16(p8[qb], vf, o_acc[qb][hb]);
      }
      __builtin_amdgcn_s_setprio(0);
    }

    // ---- cross-wave combine (partials over s add; static max) ----
    __syncthreads();  // LDS reads of last tile complete; Ks/Vs reusable
    float* obuf = (float*)(&Ks[0][0]);    // 4 slots x 2048 floats = 32KB
    float* lbuf = (float*)(&Vs[0][0]);    // 256 floats
    // l: reduce over quads, publish per-wave partials
#pragma unroll
    for (int qb = 0; qb < 4; ++qb) {
      l_lane[qb] += __shfl_xor(l_lane[qb], 16, 64);
      l_lane[qb] += __shfl_xor(l_lane[qb], 32, 64);
    }
    if (quad == 0) {
#pragma unroll
      for (int qb = 0; qb < 4; ++qb)
        lbuf[w * 64 + qb * 16 + l16] = l_lane[qb];
    }
    // O: 3 rounds; wave w ends with full O for qb=w
#pragma unroll
    for (int r = 1; r < 4; ++r) {
      const int sq = (w + r) & 3;
      float* slot = obuf + sq * 2048;
#pragma unroll
      for (int hb = 0; hb < 8; ++hb)
        *reinterpret_cast<fp32x4*>(&slot[hb * 256 + lane * 4]) = o_acc[sq][hb];
      __syncthreads();
      float* mine = obuf + w * 2048;      // written by wave (w-r)&3
#pragma unroll
      for (int hb = 0; hb < 8; ++hb) {
        const fp32x4 t = *reinterpret_cast<const fp32x4*>(&mine[hb * 256 + lane * 4]);
        o_acc[w][hb] += t;
      }
      __syncthreads();
    }
    // normalize + write: wave w owns qb=w; lane: q=w*16+quad*4+i, h=hb*16+l16
    float inv[4];
#pragma unroll
    for (int i = 0; i < 4; ++i) {
      const int qq = w * 16 + quad * 4 + i;
      const float lt = lbuf[qq] + lbuf[64 + qq] + lbuf[128 + qq] + lbuf[192 + qq];
      inv[i] = (lt > 0.f) ? 1.f / lt : 0.f;
    }
#pragma unroll
    for (int hb = 0; hb < 8; ++hb)
#pragma unroll
      for (int i = 0; i < 4; ++i) {
        const int t = t0 + w * 16 + quad * 4 + i;
        Obuf[(size_t)(b * Tq + t) * 2048 + qh * Hq + hb * 16 + l16] =
            f2b(o_acc[w][hb][i] * inv[i]);
      }
    // loop-top __syncthreads of the next half protects Ks/Vs reuse
  }
}

// ---------------- launcher --------------------------------------------------

extern "C" void kernel_launch(void* const* d_in, const int* in_sizes, int n_in,
                              void* d_out, int out_size, void* d_ws, size_t ws_size,
                              hipStream_t stream) {
  const float* x = (const float*)d_in[0];
  const int* seg = (const int*)d_in[1];
  const float* wq = (const float*)d_in[2];
  const float* wk = (const float*)d_in[3];
  const float* wv = (const float*)d_in[4];
  const float* wo = (const float*)d_in[5];
  const float* q_scale = (const float*)d_in[6];
  const float* k_scale = (const float*)d_in[7];
  float* out = (float*)d_out;

  char* ws = (char*)d_ws;
  u16* xb = (u16*)(ws);                              //  8 MB: x bf16 (4096x1024)
  u16* wqkv_t = (u16*)(ws + 8388608);                //  8 MB: fused B^T (4096x1024)
  u16* qkv = (u16*)(ws + 16777216);                  // 32 MB: q|k (v region unused)
  u16* vt = (u16*)(ws + 50331648);                   //  8 MB: v^T (2,8,128,2048)
  u16* wo_t = (u16*)(ws + 58720256);                 //  4 MB: wo^T (1024x2048)
  u16* Obuf = (u16*)(ws + 62914560);                 // 16 MB: attn out (4096x2048)
  int* posb = (int*)(ws + 79691776);                 // 16 KB: positions

  // merged prep: cast x, transpose wq/wk/wv + wo, positions
  prep_kernel<<<10242, 256, 0, stream>>>(x, wq, wk, wv, wo, seg,
                                         xb, wqkv_t, wo_t, posb);

  // QKV projection + fused RMSNorm/RoPE/v-transpose
  gemm_qkv_kernel<<<dim3(32, 32, 1), 256, 0, stream>>>(
      xb, wqkv_t, qkv, vt, posb, q_scale, k_scale);

  // flash attention: 512 uniform 17-tile blocks, 2 blocks/CU sustained
  flash_kernel<<<512, 256, 0, stream>>>(qkv, vt, posb, seg, Obuf);

  // output projection: (4096x2048) x (1024x2048)^T -> 4096x1024 fp32
  gemm_out_kernel<<<dim3(16, 32, 1), 256, 0, stream>>>(Obuf, wo_t, out);
}

// Round 4
// 377.866 us; speedup vs baseline: 1.4480x; 1.4480x over previous
//
#include <hip/hip_runtime.h>
#include <hip/hip_bf16.h>

// ---------------------------------------------------------------------------
// Fused GQA attention block for B=2,T=2048,D=1024,N=16,K=8,H=128 on gfx950.
// R14: R13's swapped-operand flash was correct but its cross-wave combine
// indexed o_acc with RUNTIME indices (o_acc[sq], o_acc[w]) -> the whole
// 128-VGPR accumulator was allocated in scratch (VGPR_Count fell to 128,
// 2 GB of HBM spill traffic, 6x regression). R14 keeps the structure and
// makes every register index compile-time: combine loops qb statically,
// waves w!=qb publish o_acc[qb] to LDS slot w (runtime LDS ADDRESS is
// fine), wave w==qb accumulates with a static ww loop and writes its 16
// rows inside the branch.
// ---------------------------------------------------------------------------

typedef unsigned short u16;
typedef __attribute__((ext_vector_type(8))) short s16x8;   // 8 bf16 = 4 VGPRs (MFMA A/B frag)
typedef __attribute__((ext_vector_type(4))) float fp32x4;  // MFMA C/D frag
typedef __attribute__((ext_vector_type(4))) u16 u16x4;

#define MFMA_BF16(a, b, c) __builtin_amdgcn_mfma_f32_16x16x32_bf16((a), (b), (c), 0, 0, 0)

static constexpr int Bq = 2, Tq = 2048, Dq = 1024, NHq = 16, KHq = 8, Hq = 128;
static constexpr float EPSq = 1e-6f;
// exp2 domain: logits scaled by SCALE*log2(e); softmax invariant to the base.
static constexpr float S2q = 0.08838834764831845f * 1.4426950408889634f;
static constexpr float MAXq = 20.0f;   // static softmax max (exp2 domain)
static constexpr float NEGHUGE = -3.0e38f;

__device__ __forceinline__ u16 f2b(float f) {
  __hip_bfloat16 h = __float2bfloat16(f);
  return *reinterpret_cast<u16*>(&h);
}

// async global->LDS, 16B per lane; LDS dest = wave-uniform base + lane*16.
__device__ __forceinline__ void gload16(const u16* g, u16* lds_base) {
  __builtin_amdgcn_global_load_lds(
      (const __attribute__((address_space(1))) unsigned int*)(const void*)g,
      (__attribute__((address_space(3))) unsigned int*)(void*)lds_base, 16, 0, 0);
}

// ---------------- merged prep kernel ----------------------------------------
// blocks [0,4096):    cast x -> bf16
// blocks [4096,8192):  wq|wk|wv transpose-cast into fused B^T (4096x1024)
// blocks [8192,10240): wo transpose-cast -> wo_t (1024x2048)
// blocks [10240,10242): positions from segment_ids

__global__ __launch_bounds__(256) void prep_kernel(
    const float* __restrict__ x, const float* __restrict__ wq,
    const float* __restrict__ wk, const float* __restrict__ wv,
    const float* __restrict__ wo, const int* __restrict__ seg,
    u16* __restrict__ xb, u16* __restrict__ wqkv_t, u16* __restrict__ wo_t,
    int* __restrict__ pos) {
  const int bid = blockIdx.x;
  const int tid = threadIdx.x;
  if (bid < 4096) {
    const int i = bid * 1024 + tid * 4;
    const float4 v = *reinterpret_cast<const float4*>(x + i);
    u16x4 o;
    o.x = f2b(v.x); o.y = f2b(v.y); o.z = f2b(v.z); o.w = f2b(v.w);
    *reinterpret_cast<u16x4*>(xb + i) = o;
    return;
  }
  __shared__ float tile[32][33];
  __shared__ int sv[256], si[256];
  const int tx = tid & 31, ty = tid >> 5;
  if (bid < 8192) {
    const int z = bid - 4096;
    const int r0 = (z & 31) * 32;   // D block
    const int c0 = (z >> 5) * 32;   // weight col block (0..4095)
    const float* src;
    int stride, coff;
    if (c0 < 2048)      { src = wq; stride = 2048; coff = c0; }
    else if (c0 < 3072) { src = wk; stride = 1024; coff = c0 - 2048; }
    else                { src = wv; stride = 1024; coff = c0 - 3072; }
#pragma unroll
    for (int j = 0; j < 32; j += 8)
      tile[ty + j][tx] = src[(long)(r0 + ty + j) * stride + (coff + tx)];
    __syncthreads();
#pragma unroll
    for (int j = 0; j < 32; j += 8)
      wqkv_t[(long)(c0 + ty + j) * 1024 + (r0 + tx)] = f2b(tile[tx][ty + j]);
    return;
  }
  if (bid < 10240) {
    const int z = bid - 8192;
    const int c0 = (z & 31) * 32;   // D col block (dst row, 0..1023)
    const int r0 = (z >> 5) * 32;   // src row block (0..2047)
#pragma unroll
    for (int j = 0; j < 32; j += 8)
      tile[ty + j][tx] = wo[(long)(r0 + ty + j) * 1024 + (c0 + tx)];
    __syncthreads();
#pragma unroll
    for (int j = 0; j < 32; j += 8)
      wo_t[(long)(c0 + ty + j) * 2048 + (r0 + tx)] = f2b(tile[tx][ty + j]);
    return;
  }
  // positions
  const int b = bid - 10240;
  const int* s = seg + b * Tq;
  int bestv = -2147483647 - 1, besti = 0x7fffffff;
  for (int t = tid; t < Tq; t += 256) {
    int v = s[t];
    if (v > bestv) { bestv = v; besti = t; }
  }
  sv[tid] = bestv; si[tid] = besti;
  __syncthreads();
  for (int k = 128; k > 0; k >>= 1) {
    if (tid < k) {
      int v2 = sv[tid + k], i2 = si[tid + k];
      if (v2 > sv[tid] || (v2 == sv[tid] && i2 < si[tid])) {
        sv[tid] = v2; si[tid] = i2;
      }
    }
    __syncthreads();
  }
  const int off = si[0];
  for (int t = tid; t < Tq; t += 256)
    pos[b * Tq + t] = (s[t] != 0) ? (t - off) : (1 << 30);
}

// ---------------- QKV GEMM + fused norm/rope/v-transpose --------------------

__global__ __launch_bounds__(256) void gemm_qkv_kernel(
    const u16* __restrict__ A, const u16* __restrict__ Bt,
    u16* __restrict__ qkv, u16* __restrict__ vt, const int* __restrict__ pos,
    const float* __restrict__ q_scale, const float* __restrict__ k_scale) {
  __shared__ __align__(16) u16 As[128][64];
  __shared__ __align__(16) u16 Bs[128][64];
  const int tid = threadIdx.x;
  const int wave = tid >> 6, lane = tid & 63;
  const int quad = lane >> 4, l16 = lane & 15;
  const int m0 = blockIdx.y * 128, n0 = blockIdx.x * 128;
  const int row8 = lane >> 3;
  const int cgl = (lane & 7) ^ row8;

  const fp32x4 z4 = {0.f, 0.f, 0.f, 0.f};
  fp32x4 acc[2][8];
#pragma unroll
  for (int i = 0; i < 2; ++i)
#pragma unroll
    for (int j = 0; j < 8; ++j) acc[i][j] = z4;

  for (int k0 = 0; k0 < 1024; k0 += 64) {
    __syncthreads();
#pragma unroll
    for (int jj = 0; jj < 4; ++jj) {
      const int R = wave * 32 + jj * 8;
      gload16(A + (size_t)(m0 + R + row8) * 1024 + k0 + cgl * 8, &As[R][0]);
      gload16(Bt + (size_t)(n0 + R + row8) * 1024 + k0 + cgl * 8, &Bs[R][0]);
    }
    __syncthreads();
#pragma unroll
    for (int kh = 0; kh < 2; ++kh) {
      s16x8 af[2], bfr[8];
#pragma unroll
      for (int i = 0; i < 2; ++i)
        af[i] = *(const s16x8*)&As[wave * 32 + i * 16 + l16]
                               [((((kh << 2) | quad) ^ (l16 & 7)) << 3)];
#pragma unroll
      for (int j = 0; j < 8; ++j)
        bfr[j] = *(const s16x8*)&Bs[j * 16 + l16]
                                [((((kh << 2) | quad) ^ (l16 & 7)) << 3)];
#pragma unroll
      for (int i = 0; i < 2; ++i)
#pragma unroll
        for (int j = 0; j < 8; ++j) acc[i][j] = MFMA_BF16(af[i], bfr[j], acc[i][j]);
    }
  }

  const int wrow = m0 + wave * 32;
  if (n0 >= 3072) {  // v tile: write transposed directly into vt
    const int kv8 = (n0 - 3072) >> 7;
    const int bq = wrow >> 11;
    const size_t vbase = (size_t)(bq * KHq + kv8) * Hq * Tq;
#pragma unroll
    for (int i = 0; i < 2; ++i) {
      const int t = (wrow + i * 16 + quad * 4) & 2047;
#pragma unroll
      for (int j = 0; j < 8; ++j) {
        const int h = j * 16 + l16;
        u16x4 o;
#pragma unroll
        for (int r = 0; r < 4; ++r) o[r] = f2b(acc[i][j][r]);
        *reinterpret_cast<u16x4*>(&vt[vbase + (size_t)h * Tq + t]) = o;
      }
    }
    return;
  }
  // q or k tile: fused RMS norm + scale + RoPE on fp32 acc
  const float* scp = (n0 < 2048) ? q_scale : k_scale;
  float scl[8];
#pragma unroll
  for (int j = 0; j < 8; ++j) scl[j] = scp[j * 16 + l16];
  float invf[4];
#pragma unroll
  for (int jf = 0; jf < 4; ++jf)  // inv_freq/(2pi): rotations per position
    invf[jf] = __builtin_amdgcn_exp2f(
                   -(float)(jf * 16 + l16) * (19.931568569324174f / 64.0f)) *
               0.15915494309189535f;
#pragma unroll
  for (int i = 0; i < 2; ++i) {
    float ss[4] = {0.f, 0.f, 0.f, 0.f};
#pragma unroll
    for (int j = 0; j < 8; ++j)
#pragma unroll
      for (int r = 0; r < 4; ++r) ss[r] += acc[i][j][r] * acc[i][j][r];
#pragma unroll
    for (int d = 1; d < 16; d <<= 1)
#pragma unroll
      for (int r = 0; r < 4; ++r) ss[r] += __shfl_xor(ss[r], d, 64);
#pragma unroll
    for (int r = 0; r < 4; ++r) {
      const int row = wrow + i * 16 + quad * 4 + r;
      const float rinv = rsqrtf(ss[r] * (1.0f / 128.0f) + EPSq);
      const float P = (float)pos[row];
      u16* orow = qkv + (size_t)row * 4096 + n0;
#pragma unroll
      for (int jf = 0; jf < 4; ++jf) {
        float rev = P * invf[jf];
        rev -= floorf(rev);
        const float s = __builtin_amdgcn_sinf(rev);
        const float c = __builtin_amdgcn_cosf(rev);
        const float a1 = acc[i][jf][r] * rinv * scl[jf];
        const float a2 = acc[i][jf + 4][r] * rinv * scl[jf + 4];
        orow[jf * 16 + l16] = f2b(a1 * c - a2 * s);
        orow[(jf + 4) * 16 + l16] = f2b(a2 * c + a1 * s);
      }
    }
  }
}

// ---------------- out-proj GEMM (fp32 out, BN=64) ---------------------------

__global__ __launch_bounds__(256) void gemm_out_kernel(
    const u16* __restrict__ A, const u16* __restrict__ Bt,
    float* __restrict__ C) {
  __shared__ __align__(16) u16 As[128][64];
  __shared__ __align__(16) u16 Bs[64][64];
  const int tid = threadIdx.x;
  const int wave = tid >> 6, lane = tid & 63;
  const int quad = lane >> 4, l16 = lane & 15;
  const int m0 = blockIdx.y * 128, n0 = blockIdx.x * 64;
  const int wm = (wave >> 1) * 64, wn = (wave & 1) * 32;
  const int row8 = lane >> 3;
  const int cgl = (lane & 7) ^ row8;

  const fp32x4 z4 = {0.f, 0.f, 0.f, 0.f};
  fp32x4 acc[4][2];
#pragma unroll
  for (int i = 0; i < 4; ++i)
#pragma unroll
    for (int j = 0; j < 2; ++j) acc[i][j] = z4;

  for (int k0 = 0; k0 < 2048; k0 += 64) {
    __syncthreads();
#pragma unroll
    for (int jj = 0; jj < 4; ++jj) {
      const int R = wave * 32 + jj * 8;
      gload16(A + (size_t)(m0 + R + row8) * 2048 + k0 + cgl * 8, &As[R][0]);
    }
#pragma unroll
    for (int jj = 0; jj < 2; ++jj) {
      const int R = wave * 16 + jj * 8;
      gload16(Bt + (size_t)(n0 + R + row8) * 2048 + k0 + cgl * 8, &Bs[R][0]);
    }
    __syncthreads();
#pragma unroll
    for (int kh = 0; kh < 2; ++kh) {
      s16x8 af[4], bfr[2];
#pragma unroll
      for (int i = 0; i < 4; ++i)
        af[i] = *(const s16x8*)&As[wm + i * 16 + l16]
                               [((((kh << 2) | quad) ^ (l16 & 7)) << 3)];
#pragma unroll
      for (int j = 0; j < 2; ++j)
        bfr[j] = *(const s16x8*)&Bs[wn + j * 16 + l16]
                                [((((kh << 2) | quad) ^ (l16 & 7)) << 3)];
#pragma unroll
      for (int i = 0; i < 4; ++i)
#pragma unroll
        for (int j = 0; j < 2; ++j) acc[i][j] = MFMA_BF16(af[i], bfr[j], acc[i][j]);
    }
  }
#pragma unroll
  for (int i = 0; i < 4; ++i) {
    const int row = m0 + wm + i * 16 + quad * 4;
#pragma unroll
    for (int j = 0; j < 2; ++j) {
      const int col = n0 + wn + j * 16 + l16;
#pragma unroll
      for (int r = 0; r < 4; ++r)
        C[(size_t)(row + r) * 1024 + col] = acc[i][j][r];
    }
  }
}

// ---------------- flash attention (swapped-operand, wave-S-split) -----------
// Grid 512: block = (b, kv, qh, pair p); chunks {31-p, p} (64 Q rows each),
// uniform 17 x 128-wide S-tiles per block. 4 waves; wave w owns the 32-s
// slice [32w,32w+32) of each tile and ALL 64 Q rows (qf[4][4] as B-frags).
// QK^T computed swapped (A=K-frag with s-row permutation sigma, B=Q) so
// each lane holds P for one q (l16) at s = quad*8+j -- exactly the
// 16x16x32 PV A-operand layout. P stays in registers (no Ps LDS, no
// lgkmcnt stall). O/l are per-wave partials over s (static max => partials
// add); combine uses ONLY compile-time register indices (rule #20).

__global__ __launch_bounds__(256, 2) void flash_kernel(
    const u16* __restrict__ qkv, const u16* __restrict__ vt,
    const int* __restrict__ pos, const int* __restrict__ seg,
    u16* __restrict__ Obuf) {
  const int tid = threadIdx.x;
  const int w = tid >> 6;
  const int lane = tid & 63;
  const int quad = lane >> 4, l16 = lane & 15;
  const int g = blockIdx.x;
  const int u = g & 31;            // unit: XCD gets 4 units = 2 K/V sets (L2-fit)
  const int b = u & 1;
  const int kv = (u >> 1) & 7;
  const int qh = kv * 2 + ((u >> 4) & 1);
  const int p = g >> 5;            // 0..15 -> chunks {31-p, p}

  __shared__ __align__(16) u16 Ks[128][128];   // [s][h-chunk ^ (s&15)]
  __shared__ __align__(16) u16 Vs[128][128];   // [h][s-chunk ^ (h&15)]

  const u16* kbase = qkv + (size_t)(b * Tq) * 4096 + 2048 + kv * Hq;
  const u16* vbase = vt + (size_t)(b * KHq + kv) * Hq * Tq;
  const int ro = lane >> 4;        // staging row offset 0..3
  const int ch = lane & 15;        // staging 16B-chunk index
  const fp32x4 z4 = {0.f, 0.f, 0.f, 0.f};

#pragma unroll
  for (int half = 0; half < 2; ++half) {
    const int c = half ? p : 31 - p;      // heavy chunk first
    const int t0 = c * 64;
    const int nst = (c + 2) >> 1;         // ceil((c+1)/2) 128-wide S-tiles

    // Q for ALL 64 chunk rows, as B-frags: lane col=l16 -> q, k=quad*8+j -> h
    s16x8 qf[4][4];
#pragma unroll
    for (int qb = 0; qb < 4; ++qb)
#pragma unroll
      for (int hk = 0; hk < 4; ++hk)
        qf[qb][hk] = *(const s16x8*)(qkv +
            (size_t)(b * Tq + t0 + qb * 16 + l16) * 4096 + qh * Hq +
            hk * 32 + quad * 8);

    fp32x4 o_acc[4][8];                   // [qb][hb] partial over wave's s
#pragma unroll
    for (int qb = 0; qb < 4; ++qb)
#pragma unroll
      for (int hb = 0; hb < 8; ++hb) o_acc[qb][hb] = z4;
    float l_lane[4] = {0.f, 0.f, 0.f, 0.f};

    for (int st = 0; st < nst; ++st) {
      const int s0 = st * 128;
      __syncthreads();  // all waves done with previous tile / combine buffers
#pragma unroll
      for (int jj = 0; jj < 8; ++jj) {
        const int R = w * 32 + jj * 4;
        const int srow = R + ro;
        gload16(kbase + (size_t)(s0 + srow) * 4096 + ((ch ^ (srow & 15)) << 3),
                &Ks[R][0]);
      }
#pragma unroll
      for (int jj = 0; jj < 8; ++jj) {
        const int R = w * 32 + jj * 4;
        const int hrow = R + ro;
        gload16(vbase + (size_t)hrow * Tq + s0 + ((ch ^ (hrow & 15)) << 3),
                &Vs[R][0]);
      }
      __syncthreads();  // drains vmcnt: tile visible

      // QK^T swapped: sc[qb][sh]; D col=l16=q, row -> s = w*32+quad*8+sh*4+r
      fp32x4 sc[4][2];
#pragma unroll
      for (int qb = 0; qb < 4; ++qb) { sc[qb][0] = z4; sc[qb][1] = z4; }
      __builtin_amdgcn_s_setprio(1);
#pragma unroll
      for (int hk = 0; hk < 4; ++hk) {
        s16x8 kf[2];
#pragma unroll
        for (int sh = 0; sh < 2; ++sh) {
          // sigma: frag row l16 -> s-row 8*(l16>>2) + 4*sh + (l16&3)
          const int srow = w * 32 + ((l16 >> 2) << 3) + (sh << 2) + (l16 & 3);
          const int hc = hk * 4 + quad;
          kf[sh] = *(const s16x8*)&Ks[srow][((hc ^ (srow & 15)) << 3)];
        }
#pragma unroll
        for (int qb = 0; qb < 4; ++qb) {
          sc[qb][0] = MFMA_BF16(kf[0], qf[qb][hk], sc[qb][0]);
          sc[qb][1] = MFMA_BF16(kf[1], qf[qb][hk], sc[qb][1]);
        }
      }
      __builtin_amdgcn_s_setprio(0);

      if (st == nst - 1) {  // diagonal tile: causal + segment mask
        int qpos[4], qseg[4];
#pragma unroll
        for (int qb = 0; qb < 4; ++qb) {
          const int q = t0 + qb * 16 + l16;
          qpos[qb] = pos[b * Tq + q];
          qseg[qb] = seg[b * Tq + q];
        }
        int spos[2][4], sseg[2][4];
#pragma unroll
        for (int sh = 0; sh < 2; ++sh)
#pragma unroll
          for (int r = 0; r < 4; ++r) {
            const int s = s0 + w * 32 + quad * 8 + sh * 4 + r;
            spos[sh][r] = pos[b * Tq + s];
            sseg[sh][r] = seg[b * Tq + s];
          }
#pragma unroll
        for (int qb = 0; qb < 4; ++qb)
#pragma unroll
          for (int sh = 0; sh < 2; ++sh)
#pragma unroll
            for (int r = 0; r < 4; ++r) {
              const bool ok = (sseg[sh][r] == qseg[qb]) &&
                              (spos[sh][r] <= qpos[qb]);
              sc[qb][sh][r] = ok ? sc[qb][sh][r] * S2q - MAXq : NEGHUGE;
            }
      } else {
#pragma unroll
        for (int qb = 0; qb < 4; ++qb)
#pragma unroll
          for (int sh = 0; sh < 2; ++sh)
#pragma unroll
            for (int r = 0; r < 4; ++r)
              sc[qb][sh][r] = sc[qb][sh][r] * S2q - MAXq;
      }

      // exp2 + in-register pack: p8[qb] element j=4*sh+r -> s=quad*8+j.
      s16x8 p8[4];
#pragma unroll
      for (int qb = 0; qb < 4; ++qb) {
#pragma unroll
        for (int sh = 0; sh < 2; ++sh)
#pragma unroll
          for (int r = 0; r < 4; ++r) {
            const float e = __builtin_amdgcn_exp2f(sc[qb][sh][r]);
            l_lane[qb] += e;
            p8[qb][sh * 4 + r] = (short)f2b(e);
          }
      }

      // PV: O[q][h] += P * V; vf lane: col=l16=h, k=quad*8+j -> s
      __builtin_amdgcn_s_setprio(1);
#pragma unroll
      for (int hb = 0; hb < 8; ++hb) {
        const int h = hb * 16 + l16;
        const int sch = w * 4 + quad;
        const s16x8 vf = *(const s16x8*)&Vs[h][((sch ^ (h & 15)) << 3)];
#pragma unroll
        for (int qb = 0; qb < 4; ++qb)
          o_acc[qb][hb] = MFMA_BF16(p8[qb], vf, o_acc[qb][hb]);
      }
      __builtin_amdgcn_s_setprio(0);
    }

    // ---- cross-wave combine (STATIC register indices only) ----
    __syncthreads();  // LDS reads of last tile complete; Ks/Vs reusable
    float* obuf = (float*)(&Ks[0][0]);    // 4 slots x 2048 floats = 32KB
    float* lbuf = (float*)(&Vs[0][0]);    // 256 floats
    // l: reduce over quads, publish per-wave partials
#pragma unroll
    for (int qb = 0; qb < 4; ++qb) {
      l_lane[qb] += __shfl_xor(l_lane[qb], 16, 64);
      l_lane[qb] += __shfl_xor(l_lane[qb], 32, 64);
    }
    if (quad == 0) {
#pragma unroll
      for (int qb = 0; qb < 4; ++qb)
        lbuf[w * 64 + qb * 16 + l16] = l_lane[qb];
    }
    // 4 static rounds; round qb: waves w!=qb publish o_acc[qb] (static
    // index; slot address w is runtime LDS addressing, which is fine),
    // wave w==qb accumulates (static ww loop) + normalizes + stores.
#pragma unroll
    for (int qb = 0; qb < 4; ++qb) {
      if (w != qb) {
        float* slot = obuf + w * 2048;
#pragma unroll
        for (int hb = 0; hb < 8; ++hb)
          *reinterpret_cast<fp32x4*>(&slot[hb * 256 + lane * 4]) = o_acc[qb][hb];
      }
      __syncthreads();
      if (w == qb) {
#pragma unroll
        for (int ww = 0; ww < 4; ++ww) {
          if (ww == qb) continue;
          const float* slot = obuf + ww * 2048;
#pragma unroll
          for (int hb = 0; hb < 8; ++hb) {
            const fp32x4 t =
                *reinterpret_cast<const fp32x4*>(&slot[hb * 256 + lane * 4]);
            o_acc[qb][hb] += t;
          }
        }
        float inv[4];
#pragma unroll
        for (int i = 0; i < 4; ++i) {
          const int qq = qb * 16 + quad * 4 + i;
          const float lt =
              lbuf[qq] + lbuf[64 + qq] + lbuf[128 + qq] + lbuf[192 + qq];
          inv[i] = (lt > 0.f) ? 1.f / lt : 0.f;
        }
#pragma unroll
        for (int hb = 0; hb < 8; ++hb)
#pragma unroll
          for (int i = 0; i < 4; ++i) {
            const int t = t0 + qb * 16 + quad * 4 + i;
            Obuf[(size_t)(b * Tq + t) * 2048 + qh * Hq + hb * 16 + l16] =
                f2b(o_acc[qb][hb][i] * inv[i]);
          }
      }
      __syncthreads();
    }
    // loop-top __syncthreads of the next half protects Ks/Vs reuse
  }
}

// ---------------- launcher --------------------------------------------------

extern "C" void kernel_launch(void* const* d_in, const int* in_sizes, int n_in,
                              void* d_out, int out_size, void* d_ws, size_t ws_size,
                              hipStream_t stream) {
  const float* x = (const float*)d_in[0];
  const int* seg = (const int*)d_in[1];
  const float* wq = (const float*)d_in[2];
  const float* wk = (const float*)d_in[3];
  const float* wv = (const float*)d_in[4];
  const float* wo = (const float*)d_in[5];
  const float* q_scale = (const float*)d_in[6];
  const float* k_scale = (const float*)d_in[7];
  float* out = (float*)d_out;

  char* ws = (char*)d_ws;
  u16* xb = (u16*)(ws);                              //  8 MB: x bf16 (4096x1024)
  u16* wqkv_t = (u16*)(ws + 8388608);                //  8 MB: fused B^T (4096x1024)
  u16* qkv = (u16*)(ws + 16777216);                  // 32 MB: q|k (v region unused)
  u16* vt = (u16*)(ws + 50331648);                   //  8 MB: v^T (2,8,128,2048)
  u16* wo_t = (u16*)(ws + 58720256);                 //  4 MB: wo^T (1024x2048)
  u16* Obuf = (u16*)(ws + 62914560);                 // 16 MB: attn out (4096x2048)
  int* posb = (int*)(ws + 79691776);                 // 16 KB: positions

  // merged prep: cast x, transpose wq/wk/wv + wo, positions
  prep_kernel<<<10242, 256, 0, stream>>>(x, wq, wk, wv, wo, seg,
                                         xb, wqkv_t, wo_t, posb);

  // QKV projection + fused RMSNorm/RoPE/v-transpose
  gemm_qkv_kernel<<<dim3(32, 32, 1), 256, 0, stream>>>(
      xb, wqkv_t, qkv, vt, posb, q_scale, k_scale);

  // flash attention: 512 uniform 17-tile blocks, 2 blocks/CU sustained
  flash_kernel<<<512, 256, 0, stream>>>(qkv, vt, posb, seg, Obuf);

  // output projection: (4096x2048) x (1024x2048)^T -> 4096x1024 fp32
  gemm_out_kernel<<<dim3(16, 32, 1), 256, 0, stream>>>(Obuf, wo_t, out);
}

// Round 5
// 225.441 us; speedup vs baseline: 2.4271x; 1.6761x over previous
//
#include <hip/hip_runtime.h>
#include <hip/hip_bf16.h>

// ---------------------------------------------------------------------------
// Fused GQA attention block for B=2,T=2048,D=1024,N=16,K=8,H=128 on gfx950.
// R15: R14 still spilled (~450MB scratch traffic): launch_bounds(256,2)
// gives 256 UNIFIED regs/wave; o_acc 128 (AGPR) + arch side ~170 > 256.
// R15 keeps the swapped-operand P-in-register structure but splits waves
// 2-way q x 2-way s: wave (qw,sw) owns 32 q rows x 64-s slice. o_acc
// halves to 64, qf to 32 -> ~175 total regs, no spill. K/V each read 2x
// per tile (128KB/tile LDS) -- fine, spill BW was the binder, not LDS.
// Combine is ONE exchange round (sw=1 -> sw=0). Sigma extends to 4
// sub-frags: s_loc = sw*64 + (sh>>1)*32 + quad*8 + (sh&1)*4 + r;
// p8[qb][sg=sh>>1][j=(sh&1)*4+r].
// ---------------------------------------------------------------------------

typedef unsigned short u16;
typedef __attribute__((ext_vector_type(8))) short s16x8;   // 8 bf16 = 4 VGPRs (MFMA A/B frag)
typedef __attribute__((ext_vector_type(4))) float fp32x4;  // MFMA C/D frag
typedef __attribute__((ext_vector_type(4))) u16 u16x4;

#define MFMA_BF16(a, b, c) __builtin_amdgcn_mfma_f32_16x16x32_bf16((a), (b), (c), 0, 0, 0)

static constexpr int Bq = 2, Tq = 2048, Dq = 1024, NHq = 16, KHq = 8, Hq = 128;
static constexpr float EPSq = 1e-6f;
// exp2 domain: logits scaled by SCALE*log2(e); softmax invariant to the base.
static constexpr float S2q = 0.08838834764831845f * 1.4426950408889634f;
static constexpr float MAXq = 20.0f;   // static softmax max (exp2 domain)
static constexpr float NEGHUGE = -3.0e38f;

__device__ __forceinline__ u16 f2b(float f) {
  __hip_bfloat16 h = __float2bfloat16(f);
  return *reinterpret_cast<u16*>(&h);
}

// async global->LDS, 16B per lane; LDS dest = wave-uniform base + lane*16.
__device__ __forceinline__ void gload16(const u16* g, u16* lds_base) {
  __builtin_amdgcn_global_load_lds(
      (const __attribute__((address_space(1))) unsigned int*)(const void*)g,
      (__attribute__((address_space(3))) unsigned int*)(void*)lds_base, 16, 0, 0);
}

// ---------------- merged prep kernel ----------------------------------------
// blocks [0,4096):    cast x -> bf16
// blocks [4096,8192):  wq|wk|wv transpose-cast into fused B^T (4096x1024)
// blocks [8192,10240): wo transpose-cast -> wo_t (1024x2048)
// blocks [10240,10242): positions from segment_ids

__global__ __launch_bounds__(256) void prep_kernel(
    const float* __restrict__ x, const float* __restrict__ wq,
    const float* __restrict__ wk, const float* __restrict__ wv,
    const float* __restrict__ wo, const int* __restrict__ seg,
    u16* __restrict__ xb, u16* __restrict__ wqkv_t, u16* __restrict__ wo_t,
    int* __restrict__ pos) {
  const int bid = blockIdx.x;
  const int tid = threadIdx.x;
  if (bid < 4096) {
    const int i = bid * 1024 + tid * 4;
    const float4 v = *reinterpret_cast<const float4*>(x + i);
    u16x4 o;
    o.x = f2b(v.x); o.y = f2b(v.y); o.z = f2b(v.z); o.w = f2b(v.w);
    *reinterpret_cast<u16x4*>(xb + i) = o;
    return;
  }
  __shared__ float tile[32][33];
  __shared__ int sv[256], si[256];
  const int tx = tid & 31, ty = tid >> 5;
  if (bid < 8192) {
    const int z = bid - 4096;
    const int r0 = (z & 31) * 32;   // D block
    const int c0 = (z >> 5) * 32;   // weight col block (0..4095)
    const float* src;
    int stride, coff;
    if (c0 < 2048)      { src = wq; stride = 2048; coff = c0; }
    else if (c0 < 3072) { src = wk; stride = 1024; coff = c0 - 2048; }
    else                { src = wv; stride = 1024; coff = c0 - 3072; }
#pragma unroll
    for (int j = 0; j < 32; j += 8)
      tile[ty + j][tx] = src[(long)(r0 + ty + j) * stride + (coff + tx)];
    __syncthreads();
#pragma unroll
    for (int j = 0; j < 32; j += 8)
      wqkv_t[(long)(c0 + ty + j) * 1024 + (r0 + tx)] = f2b(tile[tx][ty + j]);
    return;
  }
  if (bid < 10240) {
    const int z = bid - 8192;
    const int c0 = (z & 31) * 32;   // D col block (dst row, 0..1023)
    const int r0 = (z >> 5) * 32;   // src row block (0..2047)
#pragma unroll
    for (int j = 0; j < 32; j += 8)
      tile[ty + j][tx] = wo[(long)(r0 + ty + j) * 1024 + (c0 + tx)];
    __syncthreads();
#pragma unroll
    for (int j = 0; j < 32; j += 8)
      wo_t[(long)(c0 + ty + j) * 2048 + (r0 + tx)] = f2b(tile[tx][ty + j]);
    return;
  }
  // positions
  const int b = bid - 10240;
  const int* s = seg + b * Tq;
  int bestv = -2147483647 - 1, besti = 0x7fffffff;
  for (int t = tid; t < Tq; t += 256) {
    int v = s[t];
    if (v > bestv) { bestv = v; besti = t; }
  }
  sv[tid] = bestv; si[tid] = besti;
  __syncthreads();
  for (int k = 128; k > 0; k >>= 1) {
    if (tid < k) {
      int v2 = sv[tid + k], i2 = si[tid + k];
      if (v2 > sv[tid] || (v2 == sv[tid] && i2 < si[tid])) {
        sv[tid] = v2; si[tid] = i2;
      }
    }
    __syncthreads();
  }
  const int off = si[0];
  for (int t = tid; t < Tq; t += 256)
    pos[b * Tq + t] = (s[t] != 0) ? (t - off) : (1 << 30);
}

// ---------------- QKV GEMM + fused norm/rope/v-transpose --------------------

__global__ __launch_bounds__(256) void gemm_qkv_kernel(
    const u16* __restrict__ A, const u16* __restrict__ Bt,
    u16* __restrict__ qkv, u16* __restrict__ vt, const int* __restrict__ pos,
    const float* __restrict__ q_scale, const float* __restrict__ k_scale) {
  __shared__ __align__(16) u16 As[128][64];
  __shared__ __align__(16) u16 Bs[128][64];
  const int tid = threadIdx.x;
  const int wave = tid >> 6, lane = tid & 63;
  const int quad = lane >> 4, l16 = lane & 15;
  const int m0 = blockIdx.y * 128, n0 = blockIdx.x * 128;
  const int row8 = lane >> 3;
  const int cgl = (lane & 7) ^ row8;

  const fp32x4 z4 = {0.f, 0.f, 0.f, 0.f};
  fp32x4 acc[2][8];
#pragma unroll
  for (int i = 0; i < 2; ++i)
#pragma unroll
    for (int j = 0; j < 8; ++j) acc[i][j] = z4;

  for (int k0 = 0; k0 < 1024; k0 += 64) {
    __syncthreads();
#pragma unroll
    for (int jj = 0; jj < 4; ++jj) {
      const int R = wave * 32 + jj * 8;
      gload16(A + (size_t)(m0 + R + row8) * 1024 + k0 + cgl * 8, &As[R][0]);
      gload16(Bt + (size_t)(n0 + R + row8) * 1024 + k0 + cgl * 8, &Bs[R][0]);
    }
    __syncthreads();
#pragma unroll
    for (int kh = 0; kh < 2; ++kh) {
      s16x8 af[2], bfr[8];
#pragma unroll
      for (int i = 0; i < 2; ++i)
        af[i] = *(const s16x8*)&As[wave * 32 + i * 16 + l16]
                               [((((kh << 2) | quad) ^ (l16 & 7)) << 3)];
#pragma unroll
      for (int j = 0; j < 8; ++j)
        bfr[j] = *(const s16x8*)&Bs[j * 16 + l16]
                                [((((kh << 2) | quad) ^ (l16 & 7)) << 3)];
#pragma unroll
      for (int i = 0; i < 2; ++i)
#pragma unroll
        for (int j = 0; j < 8; ++j) acc[i][j] = MFMA_BF16(af[i], bfr[j], acc[i][j]);
    }
  }

  const int wrow = m0 + wave * 32;
  if (n0 >= 3072) {  // v tile: write transposed directly into vt
    const int kv8 = (n0 - 3072) >> 7;
    const int bq = wrow >> 11;
    const size_t vbase = (size_t)(bq * KHq + kv8) * Hq * Tq;
#pragma unroll
    for (int i = 0; i < 2; ++i) {
      const int t = (wrow + i * 16 + quad * 4) & 2047;
#pragma unroll
      for (int j = 0; j < 8; ++j) {
        const int h = j * 16 + l16;
        u16x4 o;
#pragma unroll
        for (int r = 0; r < 4; ++r) o[r] = f2b(acc[i][j][r]);
        *reinterpret_cast<u16x4*>(&vt[vbase + (size_t)h * Tq + t]) = o;
      }
    }
    return;
  }
  // q or k tile: fused RMS norm + scale + RoPE on fp32 acc
  const float* scp = (n0 < 2048) ? q_scale : k_scale;
  float scl[8];
#pragma unroll
  for (int j = 0; j < 8; ++j) scl[j] = scp[j * 16 + l16];
  float invf[4];
#pragma unroll
  for (int jf = 0; jf < 4; ++jf)  // inv_freq/(2pi): rotations per position
    invf[jf] = __builtin_amdgcn_exp2f(
                   -(float)(jf * 16 + l16) * (19.931568569324174f / 64.0f)) *
               0.15915494309189535f;
#pragma unroll
  for (int i = 0; i < 2; ++i) {
    float ss[4] = {0.f, 0.f, 0.f, 0.f};
#pragma unroll
    for (int j = 0; j < 8; ++j)
#pragma unroll
      for (int r = 0; r < 4; ++r) ss[r] += acc[i][j][r] * acc[i][j][r];
#pragma unroll
    for (int d = 1; d < 16; d <<= 1)
#pragma unroll
      for (int r = 0; r < 4; ++r) ss[r] += __shfl_xor(ss[r], d, 64);
#pragma unroll
    for (int r = 0; r < 4; ++r) {
      const int row = wrow + i * 16 + quad * 4 + r;
      const float rinv = rsqrtf(ss[r] * (1.0f / 128.0f) + EPSq);
      const float P = (float)pos[row];
      u16* orow = qkv + (size_t)row * 4096 + n0;
#pragma unroll
      for (int jf = 0; jf < 4; ++jf) {
        float rev = P * invf[jf];
        rev -= floorf(rev);
        const float s = __builtin_amdgcn_sinf(rev);
        const float c = __builtin_amdgcn_cosf(rev);
        const float a1 = acc[i][jf][r] * rinv * scl[jf];
        const float a2 = acc[i][jf + 4][r] * rinv * scl[jf + 4];
        orow[jf * 16 + l16] = f2b(a1 * c - a2 * s);
        orow[(jf + 4) * 16 + l16] = f2b(a2 * c + a1 * s);
      }
    }
  }
}

// ---------------- out-proj GEMM (fp32 out, BN=64) ---------------------------

__global__ __launch_bounds__(256) void gemm_out_kernel(
    const u16* __restrict__ A, const u16* __restrict__ Bt,
    float* __restrict__ C) {
  __shared__ __align__(16) u16 As[128][64];
  __shared__ __align__(16) u16 Bs[64][64];
  const int tid = threadIdx.x;
  const int wave = tid >> 6, lane = tid & 63;
  const int quad = lane >> 4, l16 = lane & 15;
  const int m0 = blockIdx.y * 128, n0 = blockIdx.x * 64;
  const int wm = (wave >> 1) * 64, wn = (wave & 1) * 32;
  const int row8 = lane >> 3;
  const int cgl = (lane & 7) ^ row8;

  const fp32x4 z4 = {0.f, 0.f, 0.f, 0.f};
  fp32x4 acc[4][2];
#pragma unroll
  for (int i = 0; i < 4; ++i)
#pragma unroll
    for (int j = 0; j < 2; ++j) acc[i][j] = z4;

  for (int k0 = 0; k0 < 2048; k0 += 64) {
    __syncthreads();
#pragma unroll
    for (int jj = 0; jj < 4; ++jj) {
      const int R = wave * 32 + jj * 8;
      gload16(A + (size_t)(m0 + R + row8) * 2048 + k0 + cgl * 8, &As[R][0]);
    }
#pragma unroll
    for (int jj = 0; jj < 2; ++jj) {
      const int R = wave * 16 + jj * 8;
      gload16(Bt + (size_t)(n0 + R + row8) * 2048 + k0 + cgl * 8, &Bs[R][0]);
    }
    __syncthreads();
#pragma unroll
    for (int kh = 0; kh < 2; ++kh) {
      s16x8 af[4], bfr[2];
#pragma unroll
      for (int i = 0; i < 4; ++i)
        af[i] = *(const s16x8*)&As[wm + i * 16 + l16]
                               [((((kh << 2) | quad) ^ (l16 & 7)) << 3)];
#pragma unroll
      for (int j = 0; j < 2; ++j)
        bfr[j] = *(const s16x8*)&Bs[wn + j * 16 + l16]
                                [((((kh << 2) | quad) ^ (l16 & 7)) << 3)];
#pragma unroll
      for (int i = 0; i < 4; ++i)
#pragma unroll
        for (int j = 0; j < 2; ++j) acc[i][j] = MFMA_BF16(af[i], bfr[j], acc[i][j]);
    }
  }
#pragma unroll
  for (int i = 0; i < 4; ++i) {
    const int row = m0 + wm + i * 16 + quad * 4;
#pragma unroll
    for (int j = 0; j < 2; ++j) {
      const int col = n0 + wn + j * 16 + l16;
#pragma unroll
      for (int r = 0; r < 4; ++r)
        C[(size_t)(row + r) * 1024 + col] = acc[i][j][r];
    }
  }
}

// ---------------- flash attention (swapped-operand, 2q x 2s wave split) -----
// Grid 512: block = (b, kv, qh, pair p); chunks {31-p, p} (64 Q rows each),
// uniform 17 x 128-wide S-tiles per block. Wave (qw=w>>1, sw=w&1) owns
// q rows [qw*32, qw*32+32) and s slice [sw*64, sw*64+64) of each tile.
// QK^T swapped (A=K sigma-permuted, B=Q): lane holds P[q=l16-col] at
// s_loc = sw*64 + (sh>>1)*32 + quad*8 + (sh&1)*4 + r -> packed in-register
// as the 16x16x32 PV A-operand p8[qb][sg][j=(sh&1)*4+r]. No P LDS. O/l
// are partials over the wave's 64-s slice (static max => add); combine is
// ONE LDS round: (qw,1) publishes, (qw,0) adds+normalizes+stores.
// Registers: o_acc 64 + qf 32 + sc 32 + p8 16 + misc ~40 << 256 unified.

__global__ __launch_bounds__(256, 2) void flash_kernel(
    const u16* __restrict__ qkv, const u16* __restrict__ vt,
    const int* __restrict__ pos, const int* __restrict__ seg,
    u16* __restrict__ Obuf) {
  const int tid = threadIdx.x;
  const int w = tid >> 6;
  const int lane = tid & 63;
  const int quad = lane >> 4, l16 = lane & 15;
  const int qw = w >> 1;           // q-half 0..1
  const int sw = w & 1;            // s-half 0..1
  const int g = blockIdx.x;
  const int u = g & 31;            // unit: XCD gets 4 units = 2 K/V sets (L2-fit)
  const int b = u & 1;
  const int kv = (u >> 1) & 7;
  const int qh = kv * 2 + ((u >> 4) & 1);
  const int p = g >> 5;            // 0..15 -> chunks {31-p, p}

  __shared__ __align__(16) u16 Ks[128][128];   // [s][h-chunk ^ (s&15)]
  __shared__ __align__(16) u16 Vs[128][128];   // [h][s-chunk ^ (h&15)]

  const u16* kbase = qkv + (size_t)(b * Tq) * 4096 + 2048 + kv * Hq;
  const u16* vbase = vt + (size_t)(b * KHq + kv) * Hq * Tq;
  const int ro = lane >> 4;        // staging row offset 0..3
  const int ch = lane & 15;        // staging 16B-chunk index
  const fp32x4 z4 = {0.f, 0.f, 0.f, 0.f};

#pragma unroll
  for (int half = 0; half < 2; ++half) {
    const int c = half ? p : 31 - p;      // heavy chunk first
    const int t0 = c * 64;
    const int nst = (c + 2) >> 1;         // ceil((c+1)/2) 128-wide S-tiles

    // Q B-frags for this wave's 32 q rows: col=l16 -> q, k=quad*8+j -> h
    s16x8 qf[2][4];
#pragma unroll
    for (int qb = 0; qb < 2; ++qb)
#pragma unroll
      for (int hk = 0; hk < 4; ++hk)
        qf[qb][hk] = *(const s16x8*)(qkv +
            (size_t)(b * Tq + t0 + qw * 32 + qb * 16 + l16) * 4096 + qh * Hq +
            hk * 32 + quad * 8);

    fp32x4 o_acc[2][8];                   // [qb][hb] partial over wave's s
#pragma unroll
    for (int qb = 0; qb < 2; ++qb)
#pragma unroll
      for (int hb = 0; hb < 8; ++hb) o_acc[qb][hb] = z4;
    float l_lane[2] = {0.f, 0.f};

    for (int st = 0; st < nst; ++st) {
      const int s0 = st * 128;
      __syncthreads();  // all waves done with previous tile / combine buffers
#pragma unroll
      for (int jj = 0; jj < 8; ++jj) {
        const int R = w * 32 + jj * 4;
        const int srow = R + ro;
        gload16(kbase + (size_t)(s0 + srow) * 4096 + ((ch ^ (srow & 15)) << 3),
                &Ks[R][0]);
      }
#pragma unroll
      for (int jj = 0; jj < 8; ++jj) {
        const int R = w * 32 + jj * 4;
        const int hrow = R + ro;
        gload16(vbase + (size_t)hrow * Tq + s0 + ((ch ^ (hrow & 15)) << 3),
                &Vs[R][0]);
      }
      __syncthreads();  // drains vmcnt: tile visible

      // QK^T swapped over this wave's 64-s slice: sc[qb][sh]
      fp32x4 sc[2][4];
#pragma unroll
      for (int qb = 0; qb < 2; ++qb)
#pragma unroll
        for (int sh = 0; sh < 4; ++sh) sc[qb][sh] = z4;
      __builtin_amdgcn_s_setprio(1);
#pragma unroll
      for (int hk = 0; hk < 4; ++hk) {
        s16x8 kf[4];
#pragma unroll
        for (int sh = 0; sh < 4; ++sh) {
          // sigma: frag row l16 -> s_loc within slice
          const int srow = sw * 64 + ((sh >> 1) << 5) + ((l16 >> 2) << 3) +
                           ((sh & 1) << 2) + (l16 & 3);
          const int hc = hk * 4 + quad;
          kf[sh] = *(const s16x8*)&Ks[srow][((hc ^ (srow & 15)) << 3)];
        }
#pragma unroll
        for (int qb = 0; qb < 2; ++qb)
#pragma unroll
          for (int sh = 0; sh < 4; ++sh)
            sc[qb][sh] = MFMA_BF16(kf[sh], qf[qb][hk], sc[qb][sh]);
      }
      __builtin_amdgcn_s_setprio(0);

      if (st == nst - 1) {  // diagonal tile: causal + segment mask
        int qpos[2], qseg[2];
#pragma unroll
        for (int qb = 0; qb < 2; ++qb) {
          const int q = t0 + qw * 32 + qb * 16 + l16;
          qpos[qb] = pos[b * Tq + q];
          qseg[qb] = seg[b * Tq + q];
        }
        int spos[4][4], sseg[4][4];
#pragma unroll
        for (int sh = 0; sh < 4; ++sh)
#pragma unroll
          for (int r = 0; r < 4; ++r) {
            const int s = s0 + sw * 64 + ((sh >> 1) << 5) + quad * 8 +
                          ((sh & 1) << 2) + r;
            spos[sh][r] = pos[b * Tq + s];
            sseg[sh][r] = seg[b * Tq + s];
          }
#pragma unroll
        for (int qb = 0; qb < 2; ++qb)
#pragma unroll
          for (int sh = 0; sh < 4; ++sh)
#pragma unroll
            for (int r = 0; r < 4; ++r) {
              const bool ok = (sseg[sh][r] == qseg[qb]) &&
                              (spos[sh][r] <= qpos[qb]);
              sc[qb][sh][r] = ok ? sc[qb][sh][r] * S2q - MAXq : NEGHUGE;
            }
      } else {
#pragma unroll
        for (int qb = 0; qb < 2; ++qb)
#pragma unroll
          for (int sh = 0; sh < 4; ++sh)
#pragma unroll
            for (int r = 0; r < 4; ++r)
              sc[qb][sh][r] = sc[qb][sh][r] * S2q - MAXq;
      }

      // exp2 + in-register pack: p8[qb][sg=sh>>1][j=(sh&1)*4+r]
      s16x8 p8[2][2];
#pragma unroll
      for (int qb = 0; qb < 2; ++qb)
#pragma unroll
        for (int sh = 0; sh < 4; ++sh)
#pragma unroll
          for (int r = 0; r < 4; ++r) {
            const float e = __builtin_amdgcn_exp2f(sc[qb][sh][r]);
            l_lane[qb] += e;
            p8[qb][sh >> 1][(sh & 1) * 4 + r] = (short)f2b(e);
          }

      // PV: O[q][h] += P*V over the wave's 64 s (2 k-groups sg=0,1)
      __builtin_amdgcn_s_setprio(1);
#pragma unroll
      for (int hb = 0; hb < 8; ++hb) {
        const int h = hb * 16 + l16;
        const int sch0 = sw * 8 + quad;
        const int sch1 = sw * 8 + 4 + quad;
        const s16x8 vf0 = *(const s16x8*)&Vs[h][((sch0 ^ (h & 15)) << 3)];
        const s16x8 vf1 = *(const s16x8*)&Vs[h][((sch1 ^ (h & 15)) << 3)];
#pragma unroll
        for (int qb = 0; qb < 2; ++qb) {
          o_acc[qb][hb] = MFMA_BF16(p8[qb][0], vf0, o_acc[qb][hb]);
          o_acc[qb][hb] = MFMA_BF16(p8[qb][1], vf1, o_acc[qb][hb]);
        }
      }
      __builtin_amdgcn_s_setprio(0);
    }

    // ---- cross-wave combine: one round, (qw,1) -> (qw,0) ----
    __syncthreads();  // LDS reads of last tile complete; Ks/Vs reusable
    float* obuf = (float*)(&Ks[0][0]);    // 2 slots x 4096 floats = 32KB
    float* lbuf = (float*)(&Vs[0][0]);    // 128 floats
    // l: reduce over quads (s-coverage), publish per-wave partials
#pragma unroll
    for (int qb = 0; qb < 2; ++qb) {
      l_lane[qb] += __shfl_xor(l_lane[qb], 16, 64);
      l_lane[qb] += __shfl_xor(l_lane[qb], 32, 64);
    }
    if (quad == 0) {
#pragma unroll
      for (int qb = 0; qb < 2; ++qb)
        lbuf[w * 32 + qb * 16 + l16] = l_lane[qb];
    }
    if (sw == 1) {
      float* slot = obuf + qw * 4096;
#pragma unroll
      for (int qb = 0; qb < 2; ++qb)
#pragma unroll
        for (int hb = 0; hb < 8; ++hb)
          *reinterpret_cast<fp32x4*>(&slot[(qb * 8 + hb) * 256 + lane * 4]) =
              o_acc[qb][hb];
    }
    __syncthreads();
    if (sw == 0) {
      const float* slot = obuf + qw * 4096;
#pragma unroll
      for (int qb = 0; qb < 2; ++qb)
#pragma unroll
        for (int hb = 0; hb < 8; ++hb) {
          const fp32x4 t = *reinterpret_cast<const fp32x4*>(
              &slot[(qb * 8 + hb) * 256 + lane * 4]);
          o_acc[qb][hb] += t;
        }
      float inv[2][4];
#pragma unroll
      for (int qb = 0; qb < 2; ++qb)
#pragma unroll
        for (int i = 0; i < 4; ++i) {
          const int idx = qb * 16 + quad * 4 + i;
          const float lt = lbuf[(qw * 2) * 32 + idx] +
                           lbuf[(qw * 2 + 1) * 32 + idx];
          inv[qb][i] = (lt > 0.f) ? 1.f / lt : 0.f;
        }
#pragma unroll
      for (int qb = 0; qb < 2; ++qb)
#pragma unroll
        for (int hb = 0; hb < 8; ++hb)
#pragma unroll
          for (int i = 0; i < 4; ++i) {
            const int t = t0 + qw * 32 + qb * 16 + quad * 4 + i;
            Obuf[(size_t)(b * Tq + t) * 2048 + qh * Hq + hb * 16 + l16] =
                f2b(o_acc[qb][hb][i] * inv[qb][i]);
          }
    }
    // next half's loop-top __syncthreads protects Ks/Vs reuse
  }
}

// ---------------- launcher --------------------------------------------------

extern "C" void kernel_launch(void* const* d_in, const int* in_sizes, int n_in,
                              void* d_out, int out_size, void* d_ws, size_t ws_size,
                              hipStream_t stream) {
  const float* x = (const float*)d_in[0];
  const int* seg = (const int*)d_in[1];
  const float* wq = (const float*)d_in[2];
  const float* wk = (const float*)d_in[3];
  const float* wv = (const float*)d_in[4];
  const float* wo = (const float*)d_in[5];
  const float* q_scale = (const float*)d_in[6];
  const float* k_scale = (const float*)d_in[7];
  float* out = (float*)d_out;

  char* ws = (char*)d_ws;
  u16* xb = (u16*)(ws);                              //  8 MB: x bf16 (4096x1024)
  u16* wqkv_t = (u16*)(ws + 8388608);                //  8 MB: fused B^T (4096x1024)
  u16* qkv = (u16*)(ws + 16777216);                  // 32 MB: q|k (v region unused)
  u16* vt = (u16*)(ws + 50331648);                   //  8 MB: v^T (2,8,128,2048)
  u16* wo_t = (u16*)(ws + 58720256);                 //  4 MB: wo^T (1024x2048)
  u16* Obuf = (u16*)(ws + 62914560);                 // 16 MB: attn out (4096x2048)
  int* posb = (int*)(ws + 79691776);                 // 16 KB: positions

  // merged prep: cast x, transpose wq/wk/wv + wo, positions
  prep_kernel<<<10242, 256, 0, stream>>>(x, wq, wk, wv, wo, seg,
                                         xb, wqkv_t, wo_t, posb);

  // QKV projection + fused RMSNorm/RoPE/v-transpose
  gemm_qkv_kernel<<<dim3(32, 32, 1), 256, 0, stream>>>(
      xb, wqkv_t, qkv, vt, posb, q_scale, k_scale);

  // flash attention: 512 uniform 17-tile blocks, 2 blocks/CU sustained
  flash_kernel<<<512, 256, 0, stream>>>(qkv, vt, posb, seg, Obuf);

  // output projection: (4096x2048) x (1024x2048)^T -> 4096x1024 fp32
  gemm_out_kernel<<<dim3(16, 32, 1), 256, 0, stream>>>(Obuf, wo_t, out);
}